// Round 6
// baseline (662.916 us; speedup 1.0000x reference)
//
#include <hip/hip_runtime.h>
#include <hip/hip_bf16.h>
#include <math.h>

typedef __hip_bfloat16 bf16;
typedef float f32x4 __attribute__((ext_vector_type(4)));
typedef float f32x2 __attribute__((ext_vector_type(2)));

#define BATCH    8
#define DIM      128
#define NFRAMES  128
#define NSAMP    32768
#define NTAB     16
#define TSIZE    512

// dual-dtype input loader (inputs measured fp32; bf16 hedge kept).
__device__ __forceinline__ float ld(const void* p, int i, bool f32) {
    return f32 ? ((const float*)p)[i] : __bfloat162float(((const bf16*)p)[i]);
}

// workspace layout (float element offsets)
#define WS_SEL    0        // 8*512 normalized selected tables
#define WS_PH2    6208     // 8*32768 float2 {phase, env*val}  (8B aligned)
// total ~2.1 MB of ws

// ---------------------------------------------------------------------------
// KA: fused heads + phase. One block per batch item (8 blocks x 1024 thr).
// All three MLPs (f64 acc), tc argmax + wavetable norm, env^2 interp, freq^2
// interp -> shuffle-scan (f64) -> packed {phase, env*val} per sample.
// ---------------------------------------------------------------------------
__global__ __launch_bounds__(1024) void kA_prep(
    const void* __restrict__ x, const void* __restrict__ wav,
    const void* tw1, const void* tb1, const void* tw2, const void* tb2,
    const void* tw3, const void* tb3,
    const void* ew1, const void* eb1, const void* ew2, const void* eb2,
    const void* ew3, const void* eb3,
    const void* fw1, const void* fb1, const void* fw2, const void* fb2,
    const void* fw3, const void* fb3,
    float* __restrict__ ws)
{
    const int b   = blockIdx.x;
    const int tid = threadIdx.x;
    const int lane = tid & 63;
    const int wid  = tid >> 6;            // 16 waves

    __shared__ int    s_isf32;
    __shared__ float  xs[DIM];
    __shared__ float  h1s[3][DIM];
    __shared__ float  h2s[3][DIM];
    __shared__ float  o3tc[256];
    __shared__ float  envf[NFRAMES];
    __shared__ float  frf[NFRAMES];
    __shared__ float  scores[16];
    __shared__ float  red[512];
    __shared__ int    s_idx;
    __shared__ float  s_val;
    __shared__ double wtot[16];

    // dtype detect: genuine bf16 N(0,1) never has |v|>=32; fp32 bits misread
    // as bf16 do with overwhelming probability.
    if (tid == 0) s_isf32 = 0;
    __syncthreads();
    {
        const unsigned short* xb = (const unsigned short*)x;
        const int e = (xb[tid] >> 7) & 0xFF;
        if (e >= 132) s_isf32 = 1;   // benign race
    }
    __syncthreads();
    const bool F32 = (s_isf32 != 0);

    if (tid < DIM) xs[tid] = ld(x, b*DIM + tid, F32);
    __syncthreads();

    const void* W1h[3] = {tw1, ew1, fw1};
    const void* B1h[3] = {tb1, eb1, fb1};
    const void* W2h[3] = {tw2, ew2, fw2};
    const void* B2h[3] = {tb2, eb2, fb2};

    // ---- layer 1, all heads in parallel (384 threads) ----
    if (tid < 384) {
        const int head = tid >> 7, o = tid & 127;
        double acc = (double)ld(B1h[head], o, F32);
        const void* W = W1h[head];
        for (int k = 0; k < DIM; k++)
            acc += (double)xs[k] * (double)ld(W, k*DIM + o, F32);
        float v = (float)acc;
        h1s[head][o] = v > 0.f ? v : 0.2f*v;
    }
    __syncthreads();

    // ---- layer 2 ----
    if (tid < 384) {
        const int head = tid >> 7, o = tid & 127;
        double acc = (double)ld(B2h[head], o, F32);
        const void* W = W2h[head];
        const float* hh = h1s[head];
        for (int k = 0; k < DIM; k++)
            acc += (double)hh[k] * (double)ld(W, k*DIM + o, F32);
        float v = (float)acc;
        h2s[head][o] = v > 0.f ? v : 0.2f*v;
    }
    __syncthreads();

    // ---- layer 3 (tc: 256 outs, env/freq: 128 each; squared at write) ----
    if (tid < 256) {
        const int o = tid;
        double acc = (double)ld(tb3, o, F32);
        const float* hh = h2s[0];
        for (int k = 0; k < DIM; k++)
            acc += (double)hh[k] * (double)ld(tw3, k*256 + o, F32);
        o3tc[o] = (float)acc;
    } else if (tid < 384) {
        const int o = tid - 256;
        double acc = (double)ld(eb3, o, F32);
        const float* hh = h2s[1];
        for (int k = 0; k < DIM; k++)
            acc += (double)hh[k] * (double)ld(ew3, k*DIM + o, F32);
        const float v = (float)acc;
        envf[o] = v * v;                 // square BEFORE interpolation
    } else if (tid < 512) {
        const int o = tid - 384;
        double acc = (double)ld(fb3, o, F32);
        const float* hh = h2s[2];
        for (int k = 0; k < DIM; k++)
            acc += (double)hh[k] * (double)ld(fw3, k*DIM + o, F32);
        const float v = (float)acc;
        frf[o] = v * v;
    }
    __syncthreads();

    // ---- tc scores -> argmax (values) ----
    if (tid < 16) {
        float s = 0.f;
        for (int j = 0; j < 16; j++) s += o3tc[tid*16 + j];
        scores[tid] = s * (1.0f/16.0f);
    }
    __syncthreads();
    if (tid == 0) {
        float best = scores[0]; int bi = 0;
        for (int i = 1; i < 16; i++)
            if (scores[i] > best) { best = scores[i]; bi = i; }  // first-max
        s_idx = bi;
        s_val = best;
    }
    __syncthreads();

    // ---- normalized selected wavetable ----
    const int idx = s_idx;
    float wv_t = 0.f;
    if (tid < 512) { wv_t = ld(wav, idx*TSIZE + tid, F32); red[tid] = wv_t; }
    __syncthreads();
    for (int off = 256; off; off >>= 1) {
        if (tid < off) red[tid] = fmaxf(red[tid], red[tid + off]);
        __syncthreads();
    }
    const float mx = red[0] + 1e-8f;
    if (tid < 512) ws[WS_SEL + b*TSIZE + tid] = wv_t / mx;

    // ---- freq^2 interp -> shuffle scan (f64) -> {phase, env*val} ----
    const int SPT = NSAMP / 1024;  // 32
    const int s0  = tid * SPT;
    float v[32];
    double local = 0.0;
    #pragma unroll
    for (int i = 0; i < SPT; i++) {
        const int s = s0 + i;
        float pos = ((float)s + 0.5f) * (1.0f/256.0f) - 0.5f;
        pos = fminf(fmaxf(pos, 0.0f), 127.0f);
        const int lo = (int)pos;
        int hi = lo + 1; if (hi > 127) hi = 127;
        const float w = pos - (float)lo;
        const float f = frf[lo]*(1.0f - w) + frf[hi]*w;
        v[i] = f;
        local += (double)f;
    }

    // inclusive wave scan of per-thread totals
    double inc = local;
    #pragma unroll
    for (int off = 1; off <= 32; off <<= 1) {
        const double u = __shfl_up(inc, off, 64);
        if (lane >= off) inc += u;
    }
    if (lane == 63) wtot[wid] = inc;
    __syncthreads();
    // exclusive scan of the 16 wave totals (single wave)
    if (tid < 16) {
        double wt = wtot[tid];
        #pragma unroll
        for (int off = 1; off <= 8; off <<= 1) {
            const double u = __shfl_up(wt, off, 16);
            if (tid >= off) wt += u;
        }
        wtot[tid] = wt - wtot[tid];   // exclusive
    }
    __syncthreads();

    double run = wtot[wid] + (inc - local);   // thread's exclusive prefix
    const float val = s_val;
    f32x2* ph2 = reinterpret_cast<f32x2*>(ws + WS_PH2) + (size_t)b * NSAMP;
    #pragma unroll
    for (int i = 0; i < SPT; i++) {
        run += (double)v[i];
        const int s = s0 + i;
        // env interp (align_corners=False), frames already squared
        float pos = ((float)s + 0.5f) * (1.0f/256.0f) - 0.5f;
        pos = fminf(fmaxf(pos, 0.0f), 127.0f);
        const int lo = (int)pos;
        int hi = lo + 1; if (hi > 127) hi = 127;
        const float w = pos - (float)lo;
        const float env = envf[lo]*(1.0f - w) + envf[hi]*w;
        f32x2 pe;
        pe.x = (float)(run - floor(run));
        pe.y = env * val;
        ph2[s] = pe;
    }
}

// ---------------------------------------------------------------------------
// KB: one wave per 4 consecutive rows. Table fragment (2 x f32x4/lane)
// hoisted across rows; nontemporal dwordx4 stores (write-once stream);
// per-row state is one uniform 8B {phase, env*val} load.
// ---------------------------------------------------------------------------
__global__ __launch_bounds__(256) void kB_synth(const float* __restrict__ ws,
                                                float* __restrict__ out)
{
    const int lane = threadIdx.x & 63;
    const int w    = (blockIdx.x << 2) + (threadIdx.x >> 6);
    const int r0   = w << 2;                 // 4 rows, never crosses batch
    const int b    = r0 >> 15;

    const float* tab = ws + WS_SEL + b*TSIZE;
    const f32x4 tv0 = *reinterpret_cast<const f32x4*>(tab + 4*lane);
    const f32x4 tv1 = *reinterpret_cast<const f32x4*>(tab + 4*lane + 256);
    const f32x2* ph2 = reinterpret_cast<const f32x2*>(ws + WS_PH2);
    float* kbase = out + (size_t)BATCH*NSAMP + ((size_t)r0 << 9);

    float samp[4];
    #pragma unroll
    for (int i = 0; i < 4; i++) {
        const int r = r0 + i;
        const f32x2 pe = ph2[r];
        const float p  = pe.x;

        float dot = 0.f;
        #pragma unroll
        for (int j = 0; j < 2; j++) {
            const int t0 = 4*lane + 256*j;
            const f32x4 tv = j ? tv1 : tv0;
            f32x4 o4;
            #pragma unroll
            for (int k = 0; k < 4; k++) {
                const float g = (float)(t0 + k) * (1.0f/511.0f);
                const float z = (g - p) * 100.0f;                 // /STD
                const float e = __expf(-0.5f*z*z) * 39.89422804014327f;
                dot += e * tv[k];
                o4[k] = e;
            }
            __builtin_nontemporal_store(o4,
                reinterpret_cast<f32x4*>(kbase + (i << 9) + t0));
        }

        #pragma unroll
        for (int m = 32; m; m >>= 1) dot += __shfl_xor(dot, m, 64);
        samp[i] = dot * pe.y;                // env*val folded in kA
    }

    if (lane == 0) {
        f32x4 s4; s4[0] = samp[0]; s4[1] = samp[1]; s4[2] = samp[2]; s4[3] = samp[3];
        *reinterpret_cast<f32x4*>(out + r0) = s4;   // r0 % 4 == 0 -> aligned
    }
}

// ---------------------------------------------------------------------------
extern "C" void kernel_launch(void* const* d_in, const int* in_sizes, int n_in,
                              void* d_out, int out_size, void* d_ws, size_t ws_size,
                              hipStream_t stream)
{
    float* ws  = (float*)d_ws;
    float* out = (float*)d_out;   // fp32 outputs per reference dtype

    hipLaunchKernelGGL(kA_prep, dim3(BATCH), dim3(1024), 0, stream,
        d_in[0], d_in[1],
        d_in[2],  d_in[3],  d_in[4],  d_in[5],  d_in[6],  d_in[7],
        d_in[8],  d_in[9],  d_in[10], d_in[11], d_in[12], d_in[13],
        d_in[14], d_in[15], d_in[16], d_in[17], d_in[18], d_in[19],
        ws);

    // 262144 rows / (4 rows/wave * 4 waves/block) = 16384 blocks
    hipLaunchKernelGGL(kB_synth, dim3((BATCH*NSAMP)/16), dim3(256), 0, stream,
        ws, out);
}